// Round 9
// baseline (299.544 us; speedup 1.0000x reference)
//
#include <hip/hip_runtime.h>
#include <cstdint>
#include <cstddef>

typedef unsigned short u16;
typedef __attribute__((ext_vector_type(8))) short short8;     // 8 bf16 in 4 VGPRs
typedef __attribute__((ext_vector_type(4))) float floatx4;    // MFMA C/D frag

#define MFMA16(a, b, c) __builtin_amdgcn_mfma_f32_16x16x32_bf16((a), (b), (c), 0, 0, 0)

// round-to-nearest-even (used for weights; memory-bound path, precision free)
__device__ __forceinline__ u16 f2bf(float f) {
    unsigned int u = __float_as_uint(f);
    u += 0x7fffu + ((u >> 16) & 1u);
    return (u16)(u >> 16);
}
// round-half-up: same 0.5-ulp worst-case bound as RNE, 2 VALU ops
__device__ __forceinline__ u16 f2bf_hu(float f) {
    return (u16)((__float_as_uint(f) + 0x8000u) >> 16);
}
// pack two f32 -> two bf16 (half-up) in one u32 via v_perm: 3 VALU ops
__device__ __forceinline__ uint32_t pack2bf_hu(float lo, float hi) {
    uint32_t ulo = __float_as_uint(lo) + 0x8000u;
    uint32_t uhi = __float_as_uint(hi) + 0x8000u;
    return __builtin_amdgcn_perm(uhi, ulo, 0x07060302u);   // {uhi[31:16], ulo[31:16]}
}

typedef const __attribute__((address_space(1))) void gvoid;
typedef __attribute__((address_space(3))) void lvoid;
__device__ __forceinline__ void gload_lds16(const void* g, void* l) {
    __builtin_amdgcn_global_load_lds((gvoid*)g, (lvoid*)l, 16, 0, 0);
}

// ---------------------------------------------------------------------------
// Mask pack: int32 mask (b,q,t2) -> bitmask u64 Mb[b][chunk=16][q=1024]
// ---------------------------------------------------------------------------
__global__ __launch_bounds__(256) void maskpack_kernel(const int* __restrict__ mask,
                                                       uint2* __restrict__ Mb) {
    const int tid = threadIdx.x;
    const int wave = tid >> 6, lane = tid & 63;
    const int qg = blockIdx.x * 4 + wave;       // global q row, 0..4095
    const int b = qg >> 10, q = qg & 1023;

    __shared__ u16 sh16[4][64];

    const int* row = mask + (size_t)qg * 1024 + lane * 16;
    unsigned m16 = 0;
#pragma unroll
    for (int i = 0; i < 4; i++) {
        int4 v = *(const int4*)(row + i * 4);
        m16 |= (v.x != 0 ? 1u : 0u) << (i * 4 + 0);
        m16 |= (v.y != 0 ? 1u : 0u) << (i * 4 + 1);
        m16 |= (v.z != 0 ? 1u : 0u) << (i * 4 + 2);
        m16 |= (v.w != 0 ? 1u : 0u) << (i * 4 + 3);
    }
    sh16[wave][lane] = (u16)m16;
    __syncthreads();
    if (lane < 16) {
        int c = lane;    // chunk
        unsigned lo = (unsigned)sh16[wave][4 * c]     | ((unsigned)sh16[wave][4 * c + 1] << 16);
        unsigned hi = (unsigned)sh16[wave][4 * c + 2] | ((unsigned)sh16[wave][4 * c + 3] << 16);
        Mb[(size_t)(b * 16 + c) * 1024 + q] = make_uint2(lo, hi);
    }
}

// ---------------------------------------------------------------------------
// Convert+transpose weights: W f32 [k][n] -> Wt bf16 [n][k].  64x64 tiles.
// ---------------------------------------------------------------------------
struct CvtTArgs { const float* src[4]; u16* dst[4]; };

__global__ __launch_bounds__(256) void cvtT_kernel(CvtTArgs a) {
    const float* src = a.src[blockIdx.z];
    u16* dst         = a.dst[blockIdx.z];
    const int c0 = blockIdx.x * 64;
    const int r0 = blockIdx.y * 64;
    const int tid = threadIdx.x;

    __shared__ __align__(16) u16 lds[64 * 72];   // +8 pad

#pragma unroll
    for (int it = 0; it < 2; it++) {
        int o = tid + it * 256;            // 512 chunks of 8
        int row = o >> 3, c8 = o & 7;
        const float* p = src + (size_t)(r0 + row) * 1024 + c0 + c8 * 8;
        float4 v0 = *(const float4*)p;
        float4 v1 = *(const float4*)(p + 4);
        u16 t[8] __attribute__((aligned(16)));
        t[0] = f2bf(v0.x); t[1] = f2bf(v0.y); t[2] = f2bf(v0.z); t[3] = f2bf(v0.w);
        t[4] = f2bf(v1.x); t[5] = f2bf(v1.y); t[6] = f2bf(v1.z); t[7] = f2bf(v1.w);
        *(uint4*)(lds + row * 72 + c8 * 8) = *(const uint4*)t;
    }
    __syncthreads();
#pragma unroll
    for (int it = 0; it < 2; it++) {
        int o = tid + it * 256;
        int i = o >> 3, j8 = o & 7;        // dst row i (= src col c0+i)
        u16 t[8] __attribute__((aligned(16)));
#pragma unroll
        for (int j = 0; j < 8; j++) t[j] = lds[(j8 * 8 + j) * 72 + i];
        *(uint4*)(dst + (size_t)(c0 + i) * 1024 + r0 + j8 * 8) = *(const uint4*)t;
    }
}

// ---------------------------------------------------------------------------
// V transpose: Vh (b,h,t,64) bf16 -> Vt (b,h,64,t) bf16.  64x64 tiles.
// ---------------------------------------------------------------------------
__global__ __launch_bounds__(256) void vtrans_kernel(const u16* __restrict__ Vh,
                                                     u16* __restrict__ Vt) {
    const size_t hoff = (size_t)blockIdx.y << 16;
    const int r0 = blockIdx.x * 64;     // t base
    const int tid = threadIdx.x;

    __shared__ __align__(16) u16 lds[64 * 72];

#pragma unroll
    for (int it = 0; it < 2; it++) {
        int o = tid + it * 256;            // 512 chunks of 8
        int row = o >> 3, c8 = o & 7;
        uint4 v = *(const uint4*)(Vh + hoff + (size_t)(r0 + row) * 64 + c8 * 8);
        *(uint4*)(lds + row * 72 + c8 * 8) = v;
    }
    __syncthreads();
#pragma unroll
    for (int it = 0; it < 2; it++) {
        int o = tid + it * 256;
        int i = o >> 3, j8 = o & 7;        // dst row i (= d), col chunk j8 (t)
        u16 t[8] __attribute__((aligned(16)));
#pragma unroll
        for (int j = 0; j < 8; j++) t[j] = lds[(j8 * 8 + j) * 72 + i];
        *(uint4*)(Vt + hoff + (size_t)i * 1024 + r0 + j8 * 8) = *(const uint4*)t;
    }
}

// ---------------------------------------------------------------------------
// QKV GEMM, WAVE-PRIVATE barrier-free (AITER-style counted-vmcnt pipeline).
// One 64-thread block = one wave = one 64x64 C tile.  Triple-buffered
// wave-private LDS; per K-step: STAGE(t+1) [8 f32-A DMAs + 4 B DMAs],
// s_waitcnt vmcnt(12) [tile t's 12 DMAs done, t+1's 12 in flight], compute.
// ZERO barriers -- waves never rendezvous; 3-buf rotation gives WAR distance
// of 3 steps.  A staged as raw f32 with source-chunk XOR swizzle (r7-verified
// math): LDS slot (row,c) holds global chunk c^(row&7); fragment read XORs
// the same and packs to bf16 at read time (VALU overlaps MFMA, no barrier
// amplification).  LDS 36 KB -> 4 blocks(waves)/CU.
// grid (1024, 3): tile = blockIdx.x (m fast: m0=(t&63)*64, n0=(t>>6)*64).
// Out: bf16 head-split out[((b*16+n/64)*1024+t)*64 + n%64], scale*(..+bias).
// ---------------------------------------------------------------------------
struct GemmArgs {
    const void* A[3];
    const u16* Wt[3];
    const float* bias[3];
    void* out[3];
    float scale[3];
};

__global__ __launch_bounds__(64) void gemm_qkv_wp(GemmArgs args) {
    const int K = 1024;
    const int z = blockIdx.y;
    const float* Af   = (const float*)args.A[z];
    const u16* Wt     = args.Wt[z];
    const float* bias = args.bias[z];
    u16* outp         = (u16*)args.out[z];
    const float scale = args.scale[z];

    const int t0 = blockIdx.x;          // 1024 tiles, m fast
    const int m0 = (t0 & 63) * 64;
    const int n0 = (t0 >> 6) * 64;
    const int lane = threadIdx.x & 63;
    const int l15 = lane & 15, quad = lane >> 4;

    __shared__ __align__(16) float lds_af[3][64 * 32];   // 24 KB, swizzled chunks
    __shared__ __align__(16) u16   lds_b [3][64 * 32];   // 12 KB

    floatx4 acc[4][4];
#pragma unroll
    for (int i = 0; i < 4; i++)
#pragma unroll
        for (int j = 0; j < 4; j++) acc[i][j] = (floatx4){0.f, 0.f, 0.f, 0.f};

    const int drow8 = lane >> 3;                 // 0..7: row within 8-row f32 group
    const int gch8  = (lane & 7) ^ drow8;        // pre-swizzled f32 SOURCE chunk
    const int drow  = lane >> 2;                 // 0..15: row within 16-row bf16 group
    const int dcol  = (lane & 3) * 8;

    const float* Ag = Af + (size_t)(m0 + drow8) * K + gch8 * 4;
    const u16*   Bg = Wt + (size_t)(n0 + drow) * K + dcol;

#define QKV_STAGE(tt) do {                                                      \
        int _buf = (tt) % 3; int _k0 = (tt) * 32;                               \
        _Pragma("unroll")                                                       \
        for (int g = 0; g < 8; g++)                                             \
            gload_lds16(Ag + (size_t)g * 8 * K + _k0, lds_af[_buf] + g * 8 * 32);\
        _Pragma("unroll")                                                       \
        for (int g = 0; g < 4; g++)                                             \
            gload_lds16(Bg + (size_t)g * 16 * K + _k0, lds_b[_buf] + g * 16 * 32);\
    } while (0)

    QKV_STAGE(0);
    for (int tt = 0; tt < 32; ++tt) {
        const int buf = tt % 3;
        if (tt < 31) {
            QKV_STAGE(tt + 1);
            __asm__ volatile("s_waitcnt vmcnt(12)" ::: "memory");  // tile tt ready
        } else {
            __asm__ volatile("s_waitcnt vmcnt(0)" ::: "memory");
        }
        __builtin_amdgcn_sched_barrier(0);

        short8 af[4], bf[4];
#pragma unroll
        for (int i = 0; i < 4; i++) {
            int row = i * 16 + l15;
            int c0 = (quad * 2) ^ (row & 7);            // swizzled slot of chunk quad*2
            const float* bp = lds_af[buf] + row * 32;
            float4 u = *(const float4*)(bp + c0 * 4);
            float4 v = *(const float4*)(bp + (c0 ^ 1) * 4);
            uint4 pk;
            pk.x = pack2bf_hu(u.x, u.y);
            pk.y = pack2bf_hu(u.z, u.w);
            pk.z = pack2bf_hu(v.x, v.y);
            pk.w = pack2bf_hu(v.z, v.w);
            af[i] = *(const short8*)&pk;
        }
#pragma unroll
        for (int j = 0; j < 4; j++)
            bf[j] = *(const short8*)(lds_b[buf] + (j * 16 + l15) * 32 + quad * 8);
#pragma unroll
        for (int i = 0; i < 4; i++)
#pragma unroll
            for (int j = 0; j < 4; j++) acc[i][j] = MFMA16(af[i], bf[j], acc[i][j]);
    }
#undef QKV_STAGE

    // epilogue.  C/D layout: col = lane&15 (n), row = quad*4 + r (m)
#pragma unroll
    for (int j = 0; j < 4; j++) {
        int n = n0 + j * 16 + l15;
        float bv = bias[n];
#pragma unroll
        for (int i = 0; i < 4; i++) {
#pragma unroll
            for (int r = 0; r < 4; r++) {
                int m = m0 + i * 16 + quad * 4 + r;
                float v = (acc[i][j][r] + bv) * scale;
                int bb = m >> 10, tq = m & 1023;
                size_t addr = ((size_t)(bb * 16 + (n >> 6)) << 16) + (size_t)tq * 64 + (n & 63);
                outp[addr] = f2bf_hu(v);
            }
        }
    }
}

// ---------------------------------------------------------------------------
// Out-projection GEMM, wave-private barrier-free.  One wave = one 64x64 tile,
// pure bf16 DMA staging (4 A + 4 B per step), triple-buffered, vmcnt(8).
// LDS 24 KB -> 6 waves/CU.  grid 1024 blocks x 64 threads (m fast).
// Out f32 [m][n].
// ---------------------------------------------------------------------------
__global__ __launch_bounds__(64) void gemm_out_wp(const u16* __restrict__ A,
                                                  const u16* __restrict__ Wt,
                                                  const float* __restrict__ bias,
                                                  float* __restrict__ out) {
    const int K = 1024;
    const int t0 = blockIdx.x;
    const int m0 = (t0 & 63) * 64;
    const int n0 = (t0 >> 6) * 64;
    const int lane = threadIdx.x & 63;
    const int l15 = lane & 15, quad = lane >> 4;

    __shared__ __align__(16) u16 lds_a[3][64 * 32];   // 12 KB
    __shared__ __align__(16) u16 lds_b[3][64 * 32];   // 12 KB

    floatx4 acc[4][4];
#pragma unroll
    for (int i = 0; i < 4; i++)
#pragma unroll
        for (int j = 0; j < 4; j++) acc[i][j] = (floatx4){0.f, 0.f, 0.f, 0.f};

    const int drow = lane >> 2;
    const int dcol = (lane & 3) * 8;

    const u16* Ag = A  + (size_t)(m0 + drow) * K + dcol;
    const u16* Bg = Wt + (size_t)(n0 + drow) * K + dcol;

#define OUT_STAGE(tt) do {                                                      \
        int _buf = (tt) % 3; int _k0 = (tt) * 32;                               \
        _Pragma("unroll")                                                       \
        for (int g = 0; g < 4; g++) {                                           \
            gload_lds16(Ag + (size_t)g * 16 * K + _k0, lds_a[_buf] + g * 16 * 32);\
            gload_lds16(Bg + (size_t)g * 16 * K + _k0, lds_b[_buf] + g * 16 * 32);\
        }                                                                       \
    } while (0)

    OUT_STAGE(0);
    for (int tt = 0; tt < 32; ++tt) {
        const int buf = tt % 3;
        if (tt < 31) {
            OUT_STAGE(tt + 1);
            __asm__ volatile("s_waitcnt vmcnt(8)" ::: "memory");   // tile tt ready
        } else {
            __asm__ volatile("s_waitcnt vmcnt(0)" ::: "memory");
        }
        __builtin_amdgcn_sched_barrier(0);

        short8 af[4], bf[4];
#pragma unroll
        for (int i = 0; i < 4; i++)
            af[i] = *(const short8*)(lds_a[buf] + (i * 16 + l15) * 32 + quad * 8);
#pragma unroll
        for (int j = 0; j < 4; j++)
            bf[j] = *(const short8*)(lds_b[buf] + (j * 16 + l15) * 32 + quad * 8);
#pragma unroll
        for (int i = 0; i < 4; i++)
#pragma unroll
            for (int j = 0; j < 4; j++) acc[i][j] = MFMA16(af[i], bf[j], acc[i][j]);
    }
#undef OUT_STAGE

    // epilogue: f32 out [m][n]
#pragma unroll
    for (int j = 0; j < 4; j++) {
        int n = n0 + j * 16 + l15;
        float bv = bias[n];
#pragma unroll
        for (int i = 0; i < 4; i++) {
#pragma unroll
            for (int r = 0; r < 4; r++) {
                int m = m0 + i * 16 + quad * 4 + r;
                out[(size_t)m * 1024 + n] = acc[i][j][r] + bv;
            }
        }
    }
}

// ---------------------------------------------------------------------------
// Flash attention (round-4 proven version, unchanged).  Non-online softmax.
// Row sums via MFMA-with-ones.  One block = 64 q-rows of one (b,h).
// grid (bh=64 fast, q-blocks=16).  Q,K: (b,h,t,64) bf16 (0.125*log2e in Q).
// Vt: (b,h,d,t) bf16.  Mask: packed bits Mb[b][chunk][q].  X: (b,t,1024) bf16.
// ---------------------------------------------------------------------------
__global__ __launch_bounds__(256) void attn_kernel(const u16* __restrict__ Q,
                                                   const u16* __restrict__ Kh,
                                                   const u16* __restrict__ Vt,
                                                   const uint2* __restrict__ Mb,
                                                   u16* __restrict__ X) {
    const int T = 1024;
    const int bh = blockIdx.x;          // fast dim: head locality per XCD
    const int b = bh >> 4, h = bh & 15;
    const int q0 = blockIdx.y * 64;
    const int tid = threadIdx.x;
    const int lane = tid & 63, wave = tid >> 6;
    const int l15 = lane & 15, quad = lane >> 4;

    __shared__ __align__(16) u16 lds_k[2][64 * 32];   // [half][t2][d-half], pitch 32
    __shared__ __align__(16) u16 lds_v[2][64 * 32];   // [half][d][t2-half], pitch 32
    __shared__ __align__(16) u16 lds_p[4][16 * 72];   // per-wave P staging

    const size_t headoff = (size_t)bh << 16;   // * 1024 * 64

    // Q fragments (A-operand): row = lane&15, k = quad*8 + j (+32 for ks=1)
    short8 aq[2];
    {
        int qrow = q0 + wave * 16 + l15;
        const u16* qp = Q + headoff + (size_t)qrow * 64 + quad * 8;
        aq[0] = *(const short8*)(qp);
        aq[1] = *(const short8*)(qp + 32);
    }

    // ones B-fragment for row-sum MFMA (bf16 1.0 = 0x3F80)
    short8 bones;
#pragma unroll
    for (int i = 0; i < 8; i++) bones[i] = (short)0x3F80;

    floatx4 O[4];
#pragma unroll
    for (int i = 0; i < 4; i++) O[i] = (floatx4){0.f, 0.f, 0.f, 0.f};
    floatx4 sums = (floatx4){0.f, 0.f, 0.f, 0.f};   // row sums, row = quad*4+r

    const int drow = lane >> 2;          // DMA: row within 16-row group
    const int dcol = (lane & 3) * 8;     // DMA: 8-elem chunk within 32
    const int rb   = wave * 16;          // this wave's 16-row staging group

    for (int j0 = 0; j0 < T; j0 += 64) {
        __syncthreads();   // previous iteration's LDS reads done
        // K halves: [t2][d-half] from Kh (row t2, d contiguous)
#pragma unroll
        for (int hf = 0; hf < 2; hf++)
            gload_lds16(Kh + headoff + (size_t)(j0 + rb + drow) * 64 + hf * 32 + dcol,
                        lds_k[hf] + rb * 32);
        // V halves: [d][t2-half] from Vt (row d, t contiguous)
#pragma unroll
        for (int hf = 0; hf < 2; hf++)
            gload_lds16(Vt + headoff + (size_t)(rb + drow) * 1024 + j0 + hf * 32 + dcol,
                        lds_v[hf] + rb * 32);
        // mask bits for this tile: lane l15 holds row (q0+rb+l15)
        uint2 mbits = Mb[(size_t)(b * 16 + (j0 >> 6)) * 1024 + q0 + rb + l15];
        __syncthreads();

        // S = Q K^T (per wave: 16 q-rows x 64 t2); scale pre-folded into Q
        floatx4 s[4];
#pragma unroll
        for (int nt = 0; nt < 4; nt++) s[nt] = (floatx4){0.f, 0.f, 0.f, 0.f};
#pragma unroll
        for (int ks = 0; ks < 2; ks++) {
#pragma unroll
            for (int nt = 0; nt < 4; nt++) {
                short8 bk = *(const short8*)(lds_k[ks] + (nt * 16 + l15) * 32 + quad * 8);
                s[nt] = MFMA16(aq[ks], bk, s[nt]);
            }
        }

        // P = exp2(S) with mask -> 0.  row = quad*4+r, bit = nt*16+l15
#pragma unroll
        for (int r = 0; r < 4; r++) {
            unsigned lo = (unsigned)__shfl((int)mbits.x, quad * 4 + r, 64);
            unsigned hi = (unsigned)__shfl((int)mbits.y, quad * 4 + r, 64);
#pragma unroll
            for (int nt = 0; nt < 4; nt++) {
                unsigned w = (nt < 2) ? lo : hi;
                unsigned bit = (w >> ((nt & 1) * 16 + l15)) & 1u;
                float p = exp2f(s[nt][r]);
                s[nt][r] = bit ? 0.f : p;
            }
        }

        // P (C-layout) -> LDS -> A-operand layout (wave-private)
        u16* pl = lds_p[wave];
#pragma unroll
        for (int nt = 0; nt < 4; nt++)
#pragma unroll
            for (int r = 0; r < 4; r++)
                pl[(quad * 4 + r) * 72 + nt * 16 + l15] = f2bf_hu(s[nt][r]);
        __asm__ volatile("s_waitcnt lgkmcnt(0)" ::: "memory");   // wave-local RAW
        __builtin_amdgcn_sched_barrier(0);                       // rule #18 fence

        // O += P @ V ; row sums += P @ ones
#pragma unroll
        for (int ks = 0; ks < 2; ks++) {
            short8 af = *(const short8*)(pl + l15 * 72 + ks * 32 + quad * 8);
            sums = MFMA16(af, bones, sums);
#pragma unroll
            for (int dt = 0; dt < 4; dt++) {
                short8 bv = *(const short8*)(lds_v[ks] + (dt * 16 + l15) * 32 + quad * 8);
                O[dt] = MFMA16(af, bv, O[dt]);
            }
        }
    }

    // epilogue: O / rowsum, write X (b, t, h*64 + d); sum==0 -> 0 (fully masked)
#pragma unroll
    for (int r = 0; r < 4; r++) {
        int q = q0 + wave * 16 + quad * 4 + r;
        float inv = (sums[r] > 0.f) ? (1.f / sums[r]) : 0.f;
#pragma unroll
        for (int dt = 0; dt < 4; dt++) {
            int d = dt * 16 + l15;
            X[(size_t)(b * 1024 + q) * 1024 + h * 64 + d] = f2bf_hu(O[dt][r] * inv);
        }
    }
}

// ---------------------------------------------------------------------------
extern "C" void kernel_launch(void* const* d_in, const int* in_sizes, int n_in,
                              void* d_out, int out_size, void* d_ws, size_t ws_size,
                              hipStream_t stream) {
    const float* query = (const float*)d_in[0];
    const float* key   = (const float*)d_in[1];
    const float* value = (const float*)d_in[2];
    const int*   mask  = (const int*)d_in[3];
    const float* Wq = (const float*)d_in[4];
    const float* bq = (const float*)d_in[5];
    const float* Wk = (const float*)d_in[6];
    const float* bk = (const float*)d_in[7];
    const float* Wv = (const float*)d_in[8];
    const float* bv = (const float*)d_in[9];
    const float* Wo = (const float*)d_in[10];
    const float* bo = (const float*)d_in[11];

    // ws (24 MiB): Wt0,Wt1,Wt2 | Wt3/Mb shared | Vt (8 MiB) | X (8 MiB)
    // d_out (16 MiB f32): Qh bf16 [0,8M) + Kh bf16 [8M,16M) until out-proj.
    // Vh (natural layout) lives in the X slot until vtrans consumes it.
    char* wsb = (char*)d_ws;
    u16* Wt0 = (u16*)wsb;
    u16* Wt1 = Wt0 + (1u << 20);
    u16* Wt2 = Wt0 + (2u << 20);
    u16* Wt3 = Wt0 + (3u << 20);
    uint2* Mbp = (uint2*)Wt3;
    u16* Vt  = (u16*)(wsb + (8u << 20));
    u16* X   = (u16*)(wsb + (16u << 20));
    u16* Vh  = X;                        // consumed by vtrans before attn writes X
    u16* Qh  = (u16*)d_out;
    u16* Kh  = (u16*)d_out + (4u << 20);

    maskpack_kernel<<<dim3(1024), dim3(256), 0, stream>>>(mask, Mbp);
    {   // convert+transpose Wq, Wk, Wv
        CvtTArgs ca{};
        ca.src[0] = Wq; ca.src[1] = Wk; ca.src[2] = Wv;
        ca.dst[0] = Wt0; ca.dst[1] = Wt1; ca.dst[2] = Wt2;
        cvtT_kernel<<<dim3(16, 16, 3), dim3(256), 0, stream>>>(ca);
    }
    {   // QKV projections (wave-private barrier-free); Q scaled by 0.125*log2(e)
        GemmArgs ga{};
        ga.A[0] = query; ga.A[1] = key; ga.A[2] = value;
        ga.Wt[0] = Wt0; ga.Wt[1] = Wt1; ga.Wt[2] = Wt2;
        ga.bias[0] = bq; ga.bias[1] = bk; ga.bias[2] = bv;
        ga.out[0] = Qh; ga.out[1] = Kh; ga.out[2] = Vh;
        ga.scale[0] = 0.125f * 1.4426950408889634f; ga.scale[1] = 1.f; ga.scale[2] = 1.f;
        gemm_qkv_wp<<<dim3(1024, 3), dim3(64), 0, stream>>>(ga);
    }
    vtrans_kernel<<<dim3(16, 64), dim3(256), 0, stream>>>(Vh, Vt);
    attn_kernel<<<dim3(64, 16), dim3(256), 0, stream>>>(Qh, Kh, Vt, Mbp, X);
    {   // convert+transpose Wo into the (now free) Wt3/Mb slot
        CvtTArgs ca{};
        ca.src[0] = Wo; ca.dst[0] = Wt3;
        cvtT_kernel<<<dim3(16, 16, 1), dim3(256), 0, stream>>>(ca);
    }
    // output projection: wave-private barrier-free 64x64 tiles
    gemm_out_wp<<<dim3(1024), dim3(64), 0, stream>>>(X, Wt3, bo, (float*)d_out);
}

// Round 10
// 251.907 us; speedup vs baseline: 1.1891x; 1.1891x over previous
//
#include <hip/hip_runtime.h>
#include <cstdint>
#include <cstddef>

typedef unsigned short u16;
typedef __attribute__((ext_vector_type(8))) short short8;     // 8 bf16 in 4 VGPRs
typedef __attribute__((ext_vector_type(4))) float floatx4;    // MFMA C/D frag

#define MFMA16(a, b, c) __builtin_amdgcn_mfma_f32_16x16x32_bf16((a), (b), (c), 0, 0, 0)

__device__ __forceinline__ u16 f2bf(float f) {
    unsigned int u = __float_as_uint(f);
    u += 0x7fffu + ((u >> 16) & 1u);
    return (u16)(u >> 16);
}
__device__ __forceinline__ u16 f2bf_hu(float f) {
    return (u16)((__float_as_uint(f) + 0x8000u) >> 16);
}
__device__ __forceinline__ uint32_t pack2bf_hu(float lo, float hi) {
    uint32_t ulo = __float_as_uint(lo) + 0x8000u;
    uint32_t uhi = __float_as_uint(hi) + 0x8000u;
    return __builtin_amdgcn_perm(uhi, ulo, 0x07060302u);   // {uhi[31:16], ulo[31:16]}
}

typedef const __attribute__((address_space(1))) void gvoid;
typedef __attribute__((address_space(3))) void lvoid;
__device__ __forceinline__ void gload_lds16(const void* g, void* l) {
    __builtin_amdgcn_global_load_lds((gvoid*)g, (lvoid*)l, 16, 0, 0);
}

// ---------------------------------------------------------------------------
// Mask pack: int32 mask (b,q,t2) -> bitmask u64 Mb[b][chunk=16][q=1024]
// ---------------------------------------------------------------------------
__global__ __launch_bounds__(256) void maskpack_kernel(const int* __restrict__ mask,
                                                       uint2* __restrict__ Mb) {
    const int tid = threadIdx.x;
    const int wave = tid >> 6, lane = tid & 63;
    const int qg = blockIdx.x * 4 + wave;
    const int b = qg >> 10, q = qg & 1023;

    __shared__ u16 sh16[4][64];

    const int* row = mask + (size_t)qg * 1024 + lane * 16;
    unsigned m16 = 0;
#pragma unroll
    for (int i = 0; i < 4; i++) {
        int4 v = *(const int4*)(row + i * 4);
        m16 |= (v.x != 0 ? 1u : 0u) << (i * 4 + 0);
        m16 |= (v.y != 0 ? 1u : 0u) << (i * 4 + 1);
        m16 |= (v.z != 0 ? 1u : 0u) << (i * 4 + 2);
        m16 |= (v.w != 0 ? 1u : 0u) << (i * 4 + 3);
    }
    sh16[wave][lane] = (u16)m16;
    __syncthreads();
    if (lane < 16) {
        int c = lane;
        unsigned lo = (unsigned)sh16[wave][4 * c]     | ((unsigned)sh16[wave][4 * c + 1] << 16);
        unsigned hi = (unsigned)sh16[wave][4 * c + 2] | ((unsigned)sh16[wave][4 * c + 3] << 16);
        Mb[(size_t)(b * 16 + c) * 1024 + q] = make_uint2(lo, hi);
    }
}

// ---------------------------------------------------------------------------
// Convert+transpose weights: W f32 [k][n] -> Wt bf16 [n][k].  64x64 tiles.
// ---------------------------------------------------------------------------
struct CvtTArgs { const float* src[4]; u16* dst[4]; };

__global__ __launch_bounds__(256) void cvtT_kernel(CvtTArgs a) {
    const float* src = a.src[blockIdx.z];
    u16* dst         = a.dst[blockIdx.z];
    const int c0 = blockIdx.x * 64;
    const int r0 = blockIdx.y * 64;
    const int tid = threadIdx.x;

    __shared__ __align__(16) u16 lds[64 * 72];

#pragma unroll
    for (int it = 0; it < 2; it++) {
        int o = tid + it * 256;
        int row = o >> 3, c8 = o & 7;
        const float* p = src + (size_t)(r0 + row) * 1024 + c0 + c8 * 8;
        float4 v0 = *(const float4*)p;
        float4 v1 = *(const float4*)(p + 4);
        u16 t[8] __attribute__((aligned(16)));
        t[0] = f2bf(v0.x); t[1] = f2bf(v0.y); t[2] = f2bf(v0.z); t[3] = f2bf(v0.w);
        t[4] = f2bf(v1.x); t[5] = f2bf(v1.y); t[6] = f2bf(v1.z); t[7] = f2bf(v1.w);
        *(uint4*)(lds + row * 72 + c8 * 8) = *(const uint4*)t;
    }
    __syncthreads();
#pragma unroll
    for (int it = 0; it < 2; it++) {
        int o = tid + it * 256;
        int i = o >> 3, j8 = o & 7;
        u16 t[8] __attribute__((aligned(16)));
#pragma unroll
        for (int j = 0; j < 8; j++) t[j] = lds[(j8 * 8 + j) * 72 + i];
        *(uint4*)(dst + (size_t)(c0 + i) * 1024 + r0 + j8 * 8) = *(const uint4*)t;
    }
}

// ---------------------------------------------------------------------------
// V transpose: Vh (b,h,t,64) bf16 -> Vt (b,h,64,t) bf16.  64x64 tiles.
// ---------------------------------------------------------------------------
__global__ __launch_bounds__(256) void vtrans_kernel(const u16* __restrict__ Vh,
                                                     u16* __restrict__ Vt) {
    const size_t hoff = (size_t)blockIdx.y << 16;
    const int r0 = blockIdx.x * 64;
    const int tid = threadIdx.x;

    __shared__ __align__(16) u16 lds[64 * 72];

#pragma unroll
    for (int it = 0; it < 2; it++) {
        int o = tid + it * 256;
        int row = o >> 3, c8 = o & 7;
        uint4 v = *(const uint4*)(Vh + hoff + (size_t)(r0 + row) * 64 + c8 * 8);
        *(uint4*)(lds + row * 72 + c8 * 8) = v;
    }
    __syncthreads();
#pragma unroll
    for (int it = 0; it < 2; it++) {
        int o = tid + it * 256;
        int i = o >> 3, j8 = o & 7;
        u16 t[8] __attribute__((aligned(16)));
#pragma unroll
        for (int j = 0; j < 8; j++) t[j] = lds[(j8 * 8 + j) * 72 + i];
        *(uint4*)(Vt + hoff + (size_t)i * 1024 + r0 + j8 * 8) = *(const uint4*)t;
    }
}

// ---------------------------------------------------------------------------
// QKV GEMM, guide-T3 "minimum 2-phase" structure (m230/m248-verified recipe):
// per K-tile: { STAGE(t+1 -> buf^1) FIRST; frag-reads(t) + pack; MFMA;
//               s_waitcnt vmcnt(0) [covered by this tile's compute]; barrier }
// ONE barrier per K-tile (r4 had two + drain with zero cover).
// BM=128, BN=256, BK=32, 512 threads = 8 waves (2m x 4n), per-wave 64x64
// acc[4][4].  A staged as RAW F32 via async DMA with source-chunk XOR swizzle
// (r7-verified math): LDS slot (row,c) holds global chunk c^(row&7); fragment
// read XORs the same and packs to bf16 in the compute phase.
// LDS 64 KB dbuf -> 2 blocks/CU = 16 waves/CU (most TLP of any config tried).
// grid (32,4,3) = 384 blocks, all resident in one round (512 slots).
// Out: bf16 head-split out[((b*16+n/64)*1024+t)*64 + n%64], scale*(..+bias).
// ---------------------------------------------------------------------------
struct GemmArgs {
    const void* A[3];
    const u16* Wt[3];
    const float* bias[3];
    void* out[3];
    float scale[3];
};

__global__ __launch_bounds__(512) void gemm_qkv_2ph(GemmArgs args) {
    const int K = 1024;
    const int z = blockIdx.z;
    const float* Af   = (const float*)args.A[z];
    const u16* Wt     = args.Wt[z];
    const float* bias = args.bias[z];
    u16* outp         = (u16*)args.out[z];
    const float scale = args.scale[z];

    const int m0 = blockIdx.x * 128;    // m fast (XCD locality)
    const int n0 = blockIdx.y * 256;
    const int tid  = threadIdx.x;
    const int lane = tid & 63;
    const int wave = tid >> 6;          // 0..7
    const int wm = wave >> 2, wn = wave & 3;   // 2m x 4n wave grid, 64x64 each
    const int l15 = lane & 15, quad = lane >> 4;

    __shared__ __align__(16) float lds_af[2][128 * 32];  // 32 KB dbuf, swizzled chunks
    __shared__ __align__(16) u16   lds_b [2][256 * 32];  // 32 KB dbuf, linear

    floatx4 acc[4][4];
#pragma unroll
    for (int i = 0; i < 4; i++)
#pragma unroll
        for (int j = 0; j < 4; j++) acc[i][j] = (floatx4){0.f, 0.f, 0.f, 0.f};

    // A staging: wave stages f32 rows [wave*16, +16) in 2 gloads of 8 rows.
    // Per gload: lane -> row (lane>>3), pre-swizzled source chunk (lane&7)^(lane>>3).
    const int ar8 = lane >> 3;
    const int agc = (lane & 7) ^ ar8;
    // B staging: wave stages bf16 rows [wave*32, +32) in 2 gloads of 16 rows.
    const int br = lane >> 2;
    const int bc = (lane & 3) * 8;

    const float* Ag = Af + (size_t)(m0 + wave * 16 + ar8) * K + agc * 4;
    const u16*   Bg = Wt + (size_t)(n0 + wave * 32 + br) * K + bc;

#define STG(bsel, tt) do {                                                     \
        int _k0 = (tt) * 32;                                                   \
        gload_lds16(Ag + _k0,                 lds_af[bsel] + (wave * 16) * 32);    \
        gload_lds16(Ag + (size_t)8 * K + _k0, lds_af[bsel] + (wave * 16 + 8) * 32);\
        gload_lds16(Bg + _k0,                  lds_b[bsel] + (wave * 32) * 32);    \
        gload_lds16(Bg + (size_t)16 * K + _k0, lds_b[bsel] + (wave * 32 + 16) * 32);\
    } while (0)

    // prologue: tile 0 -> buf 0
    STG(0, 0);
    __asm__ volatile("s_waitcnt vmcnt(0)" ::: "memory");
    __builtin_amdgcn_s_barrier();
    __builtin_amdgcn_sched_barrier(0);

    for (int t = 0; t < 32; ++t) {
        const int cur = t & 1;
        // phase top: issue next tile's stage (flies under this tile's compute)
        if (t < 31) STG(cur ^ 1, t + 1);

        // frag reads (t) + pack A f32->bf16 in the compute phase
        short8 af[4], bf[4];
#pragma unroll
        for (int i = 0; i < 4; i++) {
            int row = wm * 64 + i * 16 + l15;
            int c0 = (quad * 2) ^ (row & 7);        // swizzled slot of global chunk quad*2
            const float* bp = lds_af[cur] + row * 32;
            float4 u = *(const float4*)(bp + c0 * 4);
            float4 v = *(const float4*)(bp + (c0 ^ 1) * 4);
            uint4 pk;
            pk.x = pack2bf_hu(u.x, u.y);
            pk.y = pack2bf_hu(u.z, u.w);
            pk.z = pack2bf_hu(v.x, v.y);
            pk.w = pack2bf_hu(v.z, v.w);
            af[i] = *(const short8*)&pk;
        }
#pragma unroll
        for (int j = 0; j < 4; j++)
            bf[j] = *(const short8*)(lds_b[cur] + (wn * 64 + j * 16 + l15) * 32 + quad * 8);
#pragma unroll
        for (int i = 0; i < 4; i++)
#pragma unroll
            for (int j = 0; j < 4; j++) acc[i][j] = MFMA16(af[i], bf[j], acc[i][j]);

        // phase bottom: covered drain + single barrier
        __asm__ volatile("s_waitcnt vmcnt(0)" ::: "memory");
        __builtin_amdgcn_s_barrier();
        __builtin_amdgcn_sched_barrier(0);
    }
#undef STG

    // epilogue.  C/D layout: col = lane&15 (n), row = quad*4 + r (m)
#pragma unroll
    for (int j = 0; j < 4; j++) {
        int n = n0 + wn * 64 + j * 16 + l15;
        float bv = bias[n];
#pragma unroll
        for (int i = 0; i < 4; i++) {
#pragma unroll
            for (int r = 0; r < 4; r++) {
                int m = m0 + wm * 64 + i * 16 + quad * 4 + r;
                float v = (acc[i][j][r] + bv) * scale;
                int bb = m >> 10, tq = m & 1023;
                size_t addr = ((size_t)(bb * 16 + (n >> 6)) << 16) + (size_t)tq * 64 + (n & 63);
                outp[addr] = f2bf_hu(v);
            }
        }
    }
}

// ---------------------------------------------------------------------------
// Out-projection GEMM (round-4 exact, proven): 64x64 tile, BK=32, single LDS
// buffer, 2 barriers per K-step, pure bf16 DMA staging.
// grid (64,16) = 1024 blocks (4/CU).  Out f32 [m][n].
// ---------------------------------------------------------------------------
__global__ __launch_bounds__(256) void gemm_out_kernel(const u16* __restrict__ A,
                                                       const u16* __restrict__ Wt,
                                                       const float* __restrict__ bias,
                                                       float* __restrict__ out) {
    const int K = 1024;
    const int m0 = blockIdx.x * 64;
    const int n0 = blockIdx.y * 64;
    const int tid = threadIdx.x, lane = tid & 63, wave = tid >> 6;
    const int wm = wave >> 1, wn = wave & 1;
    const int l15 = lane & 15, quad = lane >> 4;

    __shared__ __align__(16) u16 lds_a[64 * 32];
    __shared__ __align__(16) u16 lds_b[64 * 32];

    floatx4 acc[2][2];
#pragma unroll
    for (int i = 0; i < 2; i++)
#pragma unroll
        for (int j = 0; j < 2; j++) acc[i][j] = (floatx4){0.f, 0.f, 0.f, 0.f};

    const int drow = lane >> 2;
    const int dcol = (lane & 3) * 8;

    for (int k0 = 0; k0 < K; k0 += 32) {
        __syncthreads();
        gload_lds16(A  + (size_t)(m0 + wave * 16 + drow) * K + k0 + dcol,
                    lds_a + wave * 512);
        gload_lds16(Wt + (size_t)(n0 + wave * 16 + drow) * K + k0 + dcol,
                    lds_b + wave * 512);
        __syncthreads();

        short8 af[2], bf[2];
#pragma unroll
        for (int i = 0; i < 2; i++)
            af[i] = *(const short8*)(lds_a + (wm * 32 + i * 16 + l15) * 32 + quad * 8);
#pragma unroll
        for (int j = 0; j < 2; j++)
            bf[j] = *(const short8*)(lds_b + (wn * 32 + j * 16 + l15) * 32 + quad * 8);
#pragma unroll
        for (int i = 0; i < 2; i++)
#pragma unroll
            for (int j = 0; j < 2; j++) acc[i][j] = MFMA16(af[i], bf[j], acc[i][j]);
    }

#pragma unroll
    for (int j = 0; j < 2; j++) {
        int n = n0 + wn * 32 + j * 16 + l15;
        float bv = bias[n];
#pragma unroll
        for (int i = 0; i < 2; i++) {
#pragma unroll
            for (int r = 0; r < 4; r++) {
                int m = m0 + wm * 32 + i * 16 + quad * 4 + r;
                out[(size_t)m * 1024 + n] = acc[i][j][r] + bv;
            }
        }
    }
}

// ---------------------------------------------------------------------------
// Flash attention (round-4 exact, proven).  Non-online softmax.
// Row sums via MFMA-with-ones.  One block = 64 q-rows of one (b,h).
// grid (bh=64 fast, q-blocks=16).  Q,K: (b,h,t,64) bf16 (0.125*log2e in Q).
// Vt: (b,h,d,t) bf16.  Mask: packed bits Mb[b][chunk][q].  X: (b,t,1024) bf16.
// ---------------------------------------------------------------------------
__global__ __launch_bounds__(256) void attn_kernel(const u16* __restrict__ Q,
                                                   const u16* __restrict__ Kh,
                                                   const u16* __restrict__ Vt,
                                                   const uint2* __restrict__ Mb,
                                                   u16* __restrict__ X) {
    const int T = 1024;
    const int bh = blockIdx.x;
    const int b = bh >> 4, h = bh & 15;
    const int q0 = blockIdx.y * 64;
    const int tid = threadIdx.x;
    const int lane = tid & 63, wave = tid >> 6;
    const int l15 = lane & 15, quad = lane >> 4;

    __shared__ __align__(16) u16 lds_k[2][64 * 32];
    __shared__ __align__(16) u16 lds_v[2][64 * 32];
    __shared__ __align__(16) u16 lds_p[4][16 * 72];

    const size_t headoff = (size_t)bh << 16;

    short8 aq[2];
    {
        int qrow = q0 + wave * 16 + l15;
        const u16* qp = Q + headoff + (size_t)qrow * 64 + quad * 8;
        aq[0] = *(const short8*)(qp);
        aq[1] = *(const short8*)(qp + 32);
    }

    short8 bones;
#pragma unroll
    for (int i = 0; i < 8; i++) bones[i] = (short)0x3F80;

    floatx4 O[4];
#pragma unroll
    for (int i = 0; i < 4; i++) O[i] = (floatx4){0.f, 0.f, 0.f, 0.f};
    floatx4 sums = (floatx4){0.f, 0.f, 0.f, 0.f};

    const int drow = lane >> 2;
    const int dcol = (lane & 3) * 8;
    const int rb   = wave * 16;

    for (int j0 = 0; j0 < T; j0 += 64) {
        __syncthreads();
#pragma unroll
        for (int hf = 0; hf < 2; hf++)
            gload_lds16(Kh + headoff + (size_t)(j0 + rb + drow) * 64 + hf * 32 + dcol,
                        lds_k[hf] + rb * 32);
#pragma unroll
        for (int hf = 0; hf < 2; hf++)
            gload_lds16(Vt + headoff + (size_t)(rb + drow) * 1024 + j0 + hf * 32 + dcol,
                        lds_v[hf] + rb * 32);
        uint2 mbits = Mb[(size_t)(b * 16 + (j0 >> 6)) * 1024 + q0 + rb + l15];
        __syncthreads();

        floatx4 s[4];
#pragma unroll
        for (int nt = 0; nt < 4; nt++) s[nt] = (floatx4){0.f, 0.f, 0.f, 0.f};
#pragma unroll
        for (int ks = 0; ks < 2; ks++) {
#pragma unroll
            for (int nt = 0; nt < 4; nt++) {
                short8 bk = *(const short8*)(lds_k[ks] + (nt * 16 + l15) * 32 + quad * 8);
                s[nt] = MFMA16(aq[ks], bk, s[nt]);
            }
        }

#pragma unroll
        for (int r = 0; r < 4; r++) {
            unsigned lo = (unsigned)__shfl((int)mbits.x, quad * 4 + r, 64);
            unsigned hi = (unsigned)__shfl((int)mbits.y, quad * 4 + r, 64);
#pragma unroll
            for (int nt = 0; nt < 4; nt++) {
                unsigned w = (nt < 2) ? lo : hi;
                unsigned bit = (w >> ((nt & 1) * 16 + l15)) & 1u;
                float p = exp2f(s[nt][r]);
                s[nt][r] = bit ? 0.f : p;
            }
        }

        u16* pl = lds_p[wave];
#pragma unroll
        for (int nt = 0; nt < 4; nt++)
#pragma unroll
            for (int r = 0; r < 4; r++)
                pl[(quad * 4 + r) * 72 + nt * 16 + l15] = f2bf_hu(s[nt][r]);
        __asm__ volatile("s_waitcnt lgkmcnt(0)" ::: "memory");
        __builtin_amdgcn_sched_barrier(0);

#pragma unroll
        for (int ks = 0; ks < 2; ks++) {
            short8 af = *(const short8*)(pl + l15 * 72 + ks * 32 + quad * 8);
            sums = MFMA16(af, bones, sums);
#pragma unroll
            for (int dt = 0; dt < 4; dt++) {
                short8 bv = *(const short8*)(lds_v[ks] + (dt * 16 + l15) * 32 + quad * 8);
                O[dt] = MFMA16(af, bv, O[dt]);
            }
        }
    }

#pragma unroll
    for (int r = 0; r < 4; r++) {
        int q = q0 + wave * 16 + quad * 4 + r;
        float inv = (sums[r] > 0.f) ? (1.f / sums[r]) : 0.f;
#pragma unroll
        for (int dt = 0; dt < 4; dt++) {
            int d = dt * 16 + l15;
            X[(size_t)(b * 1024 + q) * 1024 + h * 64 + d] = f2bf_hu(O[dt][r] * inv);
        }
    }
}

// ---------------------------------------------------------------------------
extern "C" void kernel_launch(void* const* d_in, const int* in_sizes, int n_in,
                              void* d_out, int out_size, void* d_ws, size_t ws_size,
                              hipStream_t stream) {
    const float* query = (const float*)d_in[0];
    const float* key   = (const float*)d_in[1];
    const float* value = (const float*)d_in[2];
    const int*   mask  = (const int*)d_in[3];
    const float* Wq = (const float*)d_in[4];
    const float* bq = (const float*)d_in[5];
    const float* Wk = (const float*)d_in[6];
    const float* bk = (const float*)d_in[7];
    const float* Wv = (const float*)d_in[8];
    const float* bv = (const float*)d_in[9];
    const float* Wo = (const float*)d_in[10];
    const float* bo = (const float*)d_in[11];

    // ws (24 MiB): Wt0,Wt1,Wt2 | Wt3/Mb shared | Vt (8 MiB) | X (8 MiB)
    // d_out (16 MiB f32): Qh bf16 [0,8M) + Kh bf16 [8M,16M) until out-proj.
    // Vh (natural layout) lives in the X slot until vtrans consumes it.
    char* wsb = (char*)d_ws;
    u16* Wt0 = (u16*)wsb;
    u16* Wt1 = Wt0 + (1u << 20);
    u16* Wt2 = Wt0 + (2u << 20);
    u16* Wt3 = Wt0 + (3u << 20);
    uint2* Mbp = (uint2*)Wt3;
    u16* Vt  = (u16*)(wsb + (8u << 20));
    u16* X   = (u16*)(wsb + (16u << 20));
    u16* Vh  = X;
    u16* Qh  = (u16*)d_out;
    u16* Kh  = (u16*)d_out + (4u << 20);

    maskpack_kernel<<<dim3(1024), dim3(256), 0, stream>>>(mask, Mbp);
    {   // convert+transpose Wq, Wk, Wv
        CvtTArgs ca{};
        ca.src[0] = Wq; ca.src[1] = Wk; ca.src[2] = Wv;
        ca.dst[0] = Wt0; ca.dst[1] = Wt1; ca.dst[2] = Wt2;
        cvtT_kernel<<<dim3(16, 16, 3), dim3(256), 0, stream>>>(ca);
    }
    {   // QKV projections (2-phase counted, 512-thread); Q scaled by 0.125*log2(e)
        GemmArgs ga{};
        ga.A[0] = query; ga.A[1] = key; ga.A[2] = value;
        ga.Wt[0] = Wt0; ga.Wt[1] = Wt1; ga.Wt[2] = Wt2;
        ga.bias[0] = bq; ga.bias[1] = bk; ga.bias[2] = bv;
        ga.out[0] = Qh; ga.out[1] = Kh; ga.out[2] = Vh;
        ga.scale[0] = 0.125f * 1.4426950408889634f; ga.scale[1] = 1.f; ga.scale[2] = 1.f;
        gemm_qkv_2ph<<<dim3(32, 4, 3), dim3(512), 0, stream>>>(ga);
    }
    vtrans_kernel<<<dim3(16, 64), dim3(256), 0, stream>>>(Vh, Vt);
    attn_kernel<<<dim3(64, 16), dim3(256), 0, stream>>>(Qh, Kh, Vt, Mbp, X);
    {   // convert+transpose Wo into the (now free) Wt3/Mb slot
        CvtTArgs ca{};
        ca.src[0] = Wo; ca.dst[0] = Wt3;
        cvtT_kernel<<<dim3(16, 16, 1), dim3(256), 0, stream>>>(ca);
    }
    // output projection (round-4 exact): 64x64 tiles, grid 1024 = 4 blocks/CU
    gemm_out_kernel<<<dim3(64, 16), dim3(256), 0, stream>>>(X, Wt3, bo, (float*)d_out);
}

// Round 11
// 250.227 us; speedup vs baseline: 1.1971x; 1.0067x over previous
//
#include <hip/hip_runtime.h>
#include <cstdint>
#include <cstddef>

typedef unsigned short u16;
typedef __attribute__((ext_vector_type(8))) short short8;     // 8 bf16 in 4 VGPRs
typedef __attribute__((ext_vector_type(4))) float floatx4;    // MFMA C/D frag

#define MFMA16(a, b, c) __builtin_amdgcn_mfma_f32_16x16x32_bf16((a), (b), (c), 0, 0, 0)

__device__ __forceinline__ u16 f2bf(float f) {
    unsigned int u = __float_as_uint(f);
    u += 0x7fffu + ((u >> 16) & 1u);
    return (u16)(u >> 16);
}
__device__ __forceinline__ u16 f2bf_hu(float f) {
    return (u16)((__float_as_uint(f) + 0x8000u) >> 16);
}
__device__ __forceinline__ uint32_t pack2bf_hu(float lo, float hi) {
    uint32_t ulo = __float_as_uint(lo) + 0x8000u;
    uint32_t uhi = __float_as_uint(hi) + 0x8000u;
    return __builtin_amdgcn_perm(uhi, ulo, 0x07060302u);   // {uhi[31:16], ulo[31:16]}
}

typedef const __attribute__((address_space(1))) void gvoid;
typedef __attribute__((address_space(3))) void lvoid;
__device__ __forceinline__ void gload_lds16(const void* g, void* l) {
    __builtin_amdgcn_global_load_lds((gvoid*)g, (lvoid*)l, 16, 0, 0);
}

// ---------------------------------------------------------------------------
// Mask pack: int32 mask (b,q,t2) -> bitmask u64 Mb[b][chunk=16][q=1024]
// ---------------------------------------------------------------------------
__global__ __launch_bounds__(256) void maskpack_kernel(const int* __restrict__ mask,
                                                       uint2* __restrict__ Mb) {
    const int tid = threadIdx.x;
    const int wave = tid >> 6, lane = tid & 63;
    const int qg = blockIdx.x * 4 + wave;
    const int b = qg >> 10, q = qg & 1023;

    __shared__ u16 sh16[4][64];

    const int* row = mask + (size_t)qg * 1024 + lane * 16;
    unsigned m16 = 0;
#pragma unroll
    for (int i = 0; i < 4; i++) {
        int4 v = *(const int4*)(row + i * 4);
        m16 |= (v.x != 0 ? 1u : 0u) << (i * 4 + 0);
        m16 |= (v.y != 0 ? 1u : 0u) << (i * 4 + 1);
        m16 |= (v.z != 0 ? 1u : 0u) << (i * 4 + 2);
        m16 |= (v.w != 0 ? 1u : 0u) << (i * 4 + 3);
    }
    sh16[wave][lane] = (u16)m16;
    __syncthreads();
    if (lane < 16) {
        int c = lane;
        unsigned lo = (unsigned)sh16[wave][4 * c]     | ((unsigned)sh16[wave][4 * c + 1] << 16);
        unsigned hi = (unsigned)sh16[wave][4 * c + 2] | ((unsigned)sh16[wave][4 * c + 3] << 16);
        Mb[(size_t)(b * 16 + c) * 1024 + q] = make_uint2(lo, hi);
    }
}

// ---------------------------------------------------------------------------
// Convert+transpose weights: W f32 [k][n] -> Wt bf16 [n][k].  64x64 tiles.
// ---------------------------------------------------------------------------
struct CvtTArgs { const float* src[4]; u16* dst[4]; };

__global__ __launch_bounds__(256) void cvtT_kernel(CvtTArgs a) {
    const float* src = a.src[blockIdx.z];
    u16* dst         = a.dst[blockIdx.z];
    const int c0 = blockIdx.x * 64;
    const int r0 = blockIdx.y * 64;
    const int tid = threadIdx.x;

    __shared__ __align__(16) u16 lds[64 * 72];

#pragma unroll
    for (int it = 0; it < 2; it++) {
        int o = tid + it * 256;
        int row = o >> 3, c8 = o & 7;
        const float* p = src + (size_t)(r0 + row) * 1024 + c0 + c8 * 8;
        float4 v0 = *(const float4*)p;
        float4 v1 = *(const float4*)(p + 4);
        u16 t[8] __attribute__((aligned(16)));
        t[0] = f2bf(v0.x); t[1] = f2bf(v0.y); t[2] = f2bf(v0.z); t[3] = f2bf(v0.w);
        t[4] = f2bf(v1.x); t[5] = f2bf(v1.y); t[6] = f2bf(v1.z); t[7] = f2bf(v1.w);
        *(uint4*)(lds + row * 72 + c8 * 8) = *(const uint4*)t;
    }
    __syncthreads();
#pragma unroll
    for (int it = 0; it < 2; it++) {
        int o = tid + it * 256;
        int i = o >> 3, j8 = o & 7;
        u16 t[8] __attribute__((aligned(16)));
#pragma unroll
        for (int j = 0; j < 8; j++) t[j] = lds[(j8 * 8 + j) * 72 + i];
        *(uint4*)(dst + (size_t)(c0 + i) * 1024 + r0 + j8 * 8) = *(const uint4*)t;
    }
}

// ---------------------------------------------------------------------------
// V transpose: Vh (b,h,t,64) bf16 -> Vt (b,h,64,t) bf16.  64x64 tiles.
// ---------------------------------------------------------------------------
__global__ __launch_bounds__(256) void vtrans_kernel(const u16* __restrict__ Vh,
                                                     u16* __restrict__ Vt) {
    const size_t hoff = (size_t)blockIdx.y << 16;
    const int r0 = blockIdx.x * 64;
    const int tid = threadIdx.x;

    __shared__ __align__(16) u16 lds[64 * 72];

#pragma unroll
    for (int it = 0; it < 2; it++) {
        int o = tid + it * 256;
        int row = o >> 3, c8 = o & 7;
        uint4 v = *(const uint4*)(Vh + hoff + (size_t)(r0 + row) * 64 + c8 * 8);
        *(uint4*)(lds + row * 72 + c8 * 8) = v;
    }
    __syncthreads();
#pragma unroll
    for (int it = 0; it < 2; it++) {
        int o = tid + it * 256;
        int i = o >> 3, j8 = o & 7;
        u16 t[8] __attribute__((aligned(16)));
#pragma unroll
        for (int j = 0; j < 8; j++) t[j] = lds[(j8 * 8 + j) * 72 + i];
        *(uint4*)(Vt + hoff + (size_t)i * 1024 + r0 + j8 * 8) = *(const uint4*)t;
    }
}

// ---------------------------------------------------------------------------
// QKV GEMM (round-10 exact, proven 64 us): guide-T3 "minimum 2-phase".
// per K-tile: { STAGE(t+1 -> buf^1) FIRST; frag-reads(t) + pack; MFMA;
//               s_waitcnt vmcnt(0) [covered by this tile's compute]; barrier }
// BM=128, BN=256, BK=32, 512 threads = 8 waves (2m x 4n), per-wave 64x64.
// A staged as RAW F32 via async DMA with source-chunk XOR swizzle; pack to
// bf16 at fragment-read time.  LDS 64 KB dbuf -> 2 blocks/CU = 16 waves/CU.
// grid (32,4,3) = 384 blocks.  Out: bf16 head-split, scale*(..+bias).
// ---------------------------------------------------------------------------
struct GemmArgs {
    const void* A[3];
    const u16* Wt[3];
    const float* bias[3];
    void* out[3];
    float scale[3];
};

__global__ __launch_bounds__(512) void gemm_qkv_2ph(GemmArgs args) {
    const int K = 1024;
    const int z = blockIdx.z;
    const float* Af   = (const float*)args.A[z];
    const u16* Wt     = args.Wt[z];
    const float* bias = args.bias[z];
    u16* outp         = (u16*)args.out[z];
    const float scale = args.scale[z];

    const int m0 = blockIdx.x * 128;
    const int n0 = blockIdx.y * 256;
    const int tid  = threadIdx.x;
    const int lane = tid & 63;
    const int wave = tid >> 6;
    const int wm = wave >> 2, wn = wave & 3;
    const int l15 = lane & 15, quad = lane >> 4;

    __shared__ __align__(16) float lds_af[2][128 * 32];
    __shared__ __align__(16) u16   lds_b [2][256 * 32];

    floatx4 acc[4][4];
#pragma unroll
    for (int i = 0; i < 4; i++)
#pragma unroll
        for (int j = 0; j < 4; j++) acc[i][j] = (floatx4){0.f, 0.f, 0.f, 0.f};

    const int ar8 = lane >> 3;
    const int agc = (lane & 7) ^ ar8;
    const int br = lane >> 2;
    const int bc = (lane & 3) * 8;

    const float* Ag = Af + (size_t)(m0 + wave * 16 + ar8) * K + agc * 4;
    const u16*   Bg = Wt + (size_t)(n0 + wave * 32 + br) * K + bc;

#define STG(bsel, tt) do {                                                     \
        int _k0 = (tt) * 32;                                                   \
        gload_lds16(Ag + _k0,                 lds_af[bsel] + (wave * 16) * 32);    \
        gload_lds16(Ag + (size_t)8 * K + _k0, lds_af[bsel] + (wave * 16 + 8) * 32);\
        gload_lds16(Bg + _k0,                  lds_b[bsel] + (wave * 32) * 32);    \
        gload_lds16(Bg + (size_t)16 * K + _k0, lds_b[bsel] + (wave * 32 + 16) * 32);\
    } while (0)

    STG(0, 0);
    __asm__ volatile("s_waitcnt vmcnt(0)" ::: "memory");
    __builtin_amdgcn_s_barrier();
    __builtin_amdgcn_sched_barrier(0);

    for (int t = 0; t < 32; ++t) {
        const int cur = t & 1;
        if (t < 31) STG(cur ^ 1, t + 1);

        short8 af[4], bf[4];
#pragma unroll
        for (int i = 0; i < 4; i++) {
            int row = wm * 64 + i * 16 + l15;
            int c0 = (quad * 2) ^ (row & 7);
            const float* bp = lds_af[cur] + row * 32;
            float4 u = *(const float4*)(bp + c0 * 4);
            float4 v = *(const float4*)(bp + (c0 ^ 1) * 4);
            uint4 pk;
            pk.x = pack2bf_hu(u.x, u.y);
            pk.y = pack2bf_hu(u.z, u.w);
            pk.z = pack2bf_hu(v.x, v.y);
            pk.w = pack2bf_hu(v.z, v.w);
            af[i] = *(const short8*)&pk;
        }
#pragma unroll
        for (int j = 0; j < 4; j++)
            bf[j] = *(const short8*)(lds_b[cur] + (wn * 64 + j * 16 + l15) * 32 + quad * 8);
#pragma unroll
        for (int i = 0; i < 4; i++)
#pragma unroll
            for (int j = 0; j < 4; j++) acc[i][j] = MFMA16(af[i], bf[j], acc[i][j]);

        __asm__ volatile("s_waitcnt vmcnt(0)" ::: "memory");
        __builtin_amdgcn_s_barrier();
        __builtin_amdgcn_sched_barrier(0);
    }
#undef STG

#pragma unroll
    for (int j = 0; j < 4; j++) {
        int n = n0 + wn * 64 + j * 16 + l15;
        float bv = bias[n];
#pragma unroll
        for (int i = 0; i < 4; i++) {
#pragma unroll
            for (int r = 0; r < 4; r++) {
                int m = m0 + wm * 64 + i * 16 + quad * 4 + r;
                float v = (acc[i][j][r] + bv) * scale;
                int bb = m >> 10, tq = m & 1023;
                size_t addr = ((size_t)(bb * 16 + (n >> 6)) << 16) + (size_t)tq * 64 + (n & 63);
                outp[addr] = f2bf_hu(v);
            }
        }
    }
}

// ---------------------------------------------------------------------------
// Out-projection GEMM (round-4 exact, proven): 64x64 tile, BK=32, single LDS
// buffer, 2 barriers per K-step, pure bf16 DMA staging.
// grid (64,16) = 1024 blocks (4/CU).  Out f32 [m][n].
// ---------------------------------------------------------------------------
__global__ __launch_bounds__(256) void gemm_out_kernel(const u16* __restrict__ A,
                                                       const u16* __restrict__ Wt,
                                                       const float* __restrict__ bias,
                                                       float* __restrict__ out) {
    const int K = 1024;
    const int m0 = blockIdx.x * 64;
    const int n0 = blockIdx.y * 64;
    const int tid = threadIdx.x, lane = tid & 63, wave = tid >> 6;
    const int wm = wave >> 1, wn = wave & 1;
    const int l15 = lane & 15, quad = lane >> 4;

    __shared__ __align__(16) u16 lds_a[64 * 32];
    __shared__ __align__(16) u16 lds_b[64 * 32];

    floatx4 acc[2][2];
#pragma unroll
    for (int i = 0; i < 2; i++)
#pragma unroll
        for (int j = 0; j < 2; j++) acc[i][j] = (floatx4){0.f, 0.f, 0.f, 0.f};

    const int drow = lane >> 2;
    const int dcol = (lane & 3) * 8;

    for (int k0 = 0; k0 < K; k0 += 32) {
        __syncthreads();
        gload_lds16(A  + (size_t)(m0 + wave * 16 + drow) * K + k0 + dcol,
                    lds_a + wave * 512);
        gload_lds16(Wt + (size_t)(n0 + wave * 16 + drow) * K + k0 + dcol,
                    lds_b + wave * 512);
        __syncthreads();

        short8 af[2], bf[2];
#pragma unroll
        for (int i = 0; i < 2; i++)
            af[i] = *(const short8*)(lds_a + (wm * 32 + i * 16 + l15) * 32 + quad * 8);
#pragma unroll
        for (int j = 0; j < 2; j++)
            bf[j] = *(const short8*)(lds_b + (wn * 32 + j * 16 + l15) * 32 + quad * 8);
#pragma unroll
        for (int i = 0; i < 2; i++)
#pragma unroll
            for (int j = 0; j < 2; j++) acc[i][j] = MFMA16(af[i], bf[j], acc[i][j]);
    }

#pragma unroll
    for (int j = 0; j < 2; j++) {
        int n = n0 + wn * 32 + j * 16 + l15;
        float bv = bias[n];
#pragma unroll
        for (int i = 0; i < 2; i++) {
#pragma unroll
            for (int r = 0; r < 4; r++) {
                int m = m0 + wm * 32 + i * 16 + quad * 4 + r;
                out[(size_t)m * 1024 + n] = acc[i][j][r] + bv;
            }
        }
    }
}

// ---------------------------------------------------------------------------
// Flash attention, QBLK=128: 512 threads = 8 waves, each wave owns 16 q-rows
// (identical per-wave math to the proven r4 kernel).  Each staged K/V tile is
// now shared by 8 waves instead of 4 -> total staged bytes and per-wave DMA
// issues HALVE (2/wave vs 4), block count halves (grid 64x8=512).
// LDS 34 KB single-buffer, 2-barrier structure (r4-exact), 16 waves/CU.
// Q,K: (b,h,t,64) bf16 (0.125*log2e in Q).  Vt: (b,h,d,t) bf16.
// Mask: packed bits Mb[b][chunk][q].  X: (b,t,1024) bf16.
// ---------------------------------------------------------------------------
__global__ __launch_bounds__(512) void attn_kernel(const u16* __restrict__ Q,
                                                   const u16* __restrict__ Kh,
                                                   const u16* __restrict__ Vt,
                                                   const uint2* __restrict__ Mb,
                                                   u16* __restrict__ X) {
    const int T = 1024;
    const int bh = blockIdx.x;          // fast dim: head locality per XCD
    const int b = bh >> 4, h = bh & 15;
    const int q0 = blockIdx.y * 128;
    const int tid = threadIdx.x;
    const int lane = tid & 63, wave = tid >> 6;   // wave 0..7
    const int l15 = lane & 15, quad = lane >> 4;

    __shared__ __align__(16) u16 lds_k[2][64 * 32];   // [d-half][t2][32]
    __shared__ __align__(16) u16 lds_v[2][64 * 32];   // [t2-half][d][32]
    __shared__ __align__(16) u16 lds_p[8][16 * 72];   // per-wave P staging

    const size_t headoff = (size_t)bh << 16;

    // Q fragments: wave owns q-rows [q0 + wave*16, +16)
    short8 aq[2];
    {
        int qrow = q0 + wave * 16 + l15;
        const u16* qp = Q + headoff + (size_t)qrow * 64 + quad * 8;
        aq[0] = *(const short8*)(qp);
        aq[1] = *(const short8*)(qp + 32);
    }

    short8 bones;
#pragma unroll
    for (int i = 0; i < 8; i++) bones[i] = (short)0x3F80;

    floatx4 O[4];
#pragma unroll
    for (int i = 0; i < 4; i++) O[i] = (floatx4){0.f, 0.f, 0.f, 0.f};
    floatx4 sums = (floatx4){0.f, 0.f, 0.f, 0.f};

    const int drow = lane >> 2;          // DMA: row within 16-row group
    const int dcol = (lane & 3) * 8;     // DMA: 8-elem chunk within 32
    // staging split across 8 waves: wave -> (half hf, 16-row group rg)
    const int shf = wave >> 2;           // 0..1
    const int srg = (wave & 3) * 16;     // 0,16,32,48

    for (int j0 = 0; j0 < T; j0 += 64) {
        __syncthreads();   // previous iteration's LDS reads done
        // K: [t2][d-half]; wave stages 16 t2-rows of its half (1 DMA)
        gload_lds16(Kh + headoff + (size_t)(j0 + srg + drow) * 64 + shf * 32 + dcol,
                    lds_k[shf] + srg * 32);
        // V: [d][t2-half]; wave stages 16 d-rows of its half (1 DMA)
        gload_lds16(Vt + headoff + (size_t)(srg + drow) * 1024 + j0 + shf * 32 + dcol,
                    lds_v[shf] + srg * 32);
        // mask bits for this tile: lane l15 holds row (q0 + wave*16 + l15)
        uint2 mbits = Mb[(size_t)(b * 16 + (j0 >> 6)) * 1024 + q0 + wave * 16 + l15];
        __syncthreads();

        // S = Q K^T (per wave: 16 q-rows x 64 t2); scale pre-folded into Q
        floatx4 s[4];
#pragma unroll
        for (int nt = 0; nt < 4; nt++) s[nt] = (floatx4){0.f, 0.f, 0.f, 0.f};
#pragma unroll
        for (int ks = 0; ks < 2; ks++) {
#pragma unroll
            for (int nt = 0; nt < 4; nt++) {
                short8 bk = *(const short8*)(lds_k[ks] + (nt * 16 + l15) * 32 + quad * 8);
                s[nt] = MFMA16(aq[ks], bk, s[nt]);
            }
        }

        // P = exp2(S) with mask -> 0.  row = quad*4+r, bit = nt*16+l15
#pragma unroll
        for (int r = 0; r < 4; r++) {
            unsigned lo = (unsigned)__shfl((int)mbits.x, quad * 4 + r, 64);
            unsigned hi = (unsigned)__shfl((int)mbits.y, quad * 4 + r, 64);
#pragma unroll
            for (int nt = 0; nt < 4; nt++) {
                unsigned w = (nt < 2) ? lo : hi;
                unsigned bit = (w >> ((nt & 1) * 16 + l15)) & 1u;
                float p = exp2f(s[nt][r]);
                s[nt][r] = bit ? 0.f : p;
            }
        }

        // P (C-layout) -> LDS -> A-operand layout (wave-private)
        u16* pl = lds_p[wave];
#pragma unroll
        for (int nt = 0; nt < 4; nt++)
#pragma unroll
            for (int r = 0; r < 4; r++)
                pl[(quad * 4 + r) * 72 + nt * 16 + l15] = f2bf_hu(s[nt][r]);
        __asm__ volatile("s_waitcnt lgkmcnt(0)" ::: "memory");   // wave-local RAW
        __builtin_amdgcn_sched_barrier(0);                       // rule #18 fence

        // O += P @ V ; row sums += P @ ones
#pragma unroll
        for (int ks = 0; ks < 2; ks++) {
            short8 af = *(const short8*)(pl + l15 * 72 + ks * 32 + quad * 8);
            sums = MFMA16(af, bones, sums);
#pragma unroll
            for (int dt = 0; dt < 4; dt++) {
                short8 bv = *(const short8*)(lds_v[ks] + (dt * 16 + l15) * 32 + quad * 8);
                O[dt] = MFMA16(af, bv, O[dt]);
            }
        }
    }

    // epilogue: O / rowsum, write X (b, t, h*64 + d); sum==0 -> 0 (fully masked)
#pragma unroll
    for (int r = 0; r < 4; r++) {
        int q = q0 + wave * 16 + quad * 4 + r;
        float inv = (sums[r] > 0.f) ? (1.f / sums[r]) : 0.f;
#pragma unroll
        for (int dt = 0; dt < 4; dt++) {
            int d = dt * 16 + l15;
            X[(size_t)(b * 1024 + q) * 1024 + h * 64 + d] = f2bf_hu(O[dt][r] * inv);
        }
    }
}

// ---------------------------------------------------------------------------
extern "C" void kernel_launch(void* const* d_in, const int* in_sizes, int n_in,
                              void* d_out, int out_size, void* d_ws, size_t ws_size,
                              hipStream_t stream) {
    const float* query = (const float*)d_in[0];
    const float* key   = (const float*)d_in[1];
    const float* value = (const float*)d_in[2];
    const int*   mask  = (const int*)d_in[3];
    const float* Wq = (const float*)d_in[4];
    const float* bq = (const float*)d_in[5];
    const float* Wk = (const float*)d_in[6];
    const float* bk = (const float*)d_in[7];
    const float* Wv = (const float*)d_in[8];
    const float* bv = (const float*)d_in[9];
    const float* Wo = (const float*)d_in[10];
    const float* bo = (const float*)d_in[11];

    // ws (24 MiB): Wt0,Wt1,Wt2 | Wt3/Mb shared | Vt (8 MiB) | X (8 MiB)
    // d_out (16 MiB f32): Qh bf16 [0,8M) + Kh bf16 [8M,16M) until out-proj.
    // Vh (natural layout) lives in the X slot until vtrans consumes it.
    char* wsb = (char*)d_ws;
    u16* Wt0 = (u16*)wsb;
    u16* Wt1 = Wt0 + (1u << 20);
    u16* Wt2 = Wt0 + (2u << 20);
    u16* Wt3 = Wt0 + (3u << 20);
    uint2* Mbp = (uint2*)Wt3;
    u16* Vt  = (u16*)(wsb + (8u << 20));
    u16* X   = (u16*)(wsb + (16u << 20));
    u16* Vh  = X;
    u16* Qh  = (u16*)d_out;
    u16* Kh  = (u16*)d_out + (4u << 20);

    maskpack_kernel<<<dim3(1024), dim3(256), 0, stream>>>(mask, Mbp);
    {   // convert+transpose Wq, Wk, Wv
        CvtTArgs ca{};
        ca.src[0] = Wq; ca.src[1] = Wk; ca.src[2] = Wv;
        ca.dst[0] = Wt0; ca.dst[1] = Wt1; ca.dst[2] = Wt2;
        cvtT_kernel<<<dim3(16, 16, 3), dim3(256), 0, stream>>>(ca);
    }
    {   // QKV projections (round-10 exact); Q scaled by 0.125*log2(e)
        GemmArgs ga{};
        ga.A[0] = query; ga.A[1] = key; ga.A[2] = value;
        ga.Wt[0] = Wt0; ga.Wt[1] = Wt1; ga.Wt[2] = Wt2;
        ga.bias[0] = bq; ga.bias[1] = bk; ga.bias[2] = bv;
        ga.out[0] = Qh; ga.out[1] = Kh; ga.out[2] = Vh;
        ga.scale[0] = 0.125f * 1.4426950408889634f; ga.scale[1] = 1.f; ga.scale[2] = 1.f;
        gemm_qkv_2ph<<<dim3(32, 4, 3), dim3(512), 0, stream>>>(ga);
    }
    vtrans_kernel<<<dim3(16, 64), dim3(256), 0, stream>>>(Vh, Vt);
    // attention: QBLK=128, 512 threads, grid 64x8 = 512 blocks
    attn_kernel<<<dim3(64, 8), dim3(512), 0, stream>>>(Qh, Kh, Vt, Mbp, X);
    {   // convert+transpose Wo into the (now free) Wt3/Mb slot
        CvtTArgs ca{};
        ca.src[0] = Wo; ca.dst[0] = Wt3;
        cvtT_kernel<<<dim3(16, 16, 1), dim3(256), 0, stream>>>(ca);
    }
    // output projection (round-4 exact): 64x64 tiles, grid 1024 = 4 blocks/CU
    gemm_out_kernel<<<dim3(64, 16), dim3(256), 0, stream>>>(X, Wt3, bo, (float*)d_out);
}